// Round 12
// baseline (838.254 us; speedup 1.0000x reference)
//
#include <hip/hip_runtime.h>

typedef __attribute__((ext_vector_type(8))) short bf16x8;
typedef __attribute__((ext_vector_type(4))) float f32x4;
typedef unsigned short ushort_t;

// ---------------------------------------------------------------------------
// fp32 -> bf16 RNE helpers
// ---------------------------------------------------------------------------
__device__ inline unsigned f2bf_rnd(float f) {
    unsigned u = __float_as_uint(f);
    return u + 0x7FFFu + ((u >> 16) & 1u);   // high 16 bits = RNE bf16
}

__device__ inline void split8(f32x4 a, f32x4 b, bf16x8& hv, bf16x8& lv) {
    float f[8] = {a.x, a.y, a.z, a.w, b.x, b.y, b.z, b.w};
    unsigned r[8], l[8];
#pragma unroll
    for (int j = 0; j < 8; ++j) r[j] = f2bf_rnd(f[j]);
#pragma unroll
    for (int j = 0; j < 8; ++j) {
        float hf = __uint_as_float(r[j] & 0xFFFF0000u);
        l[j] = f2bf_rnd(f[j] - hf);
    }
    union { unsigned u[4]; bf16x8 v; } H, L;
#pragma unroll
    for (int p = 0; p < 4; ++p) {
        H.u[p] = __builtin_amdgcn_perm(r[2 * p + 1], r[2 * p], 0x07060302u);
        L.u[p] = __builtin_amdgcn_perm(l[2 * p + 1], l[2 * p], 0x07060302u);
    }
    hv = H.v; lv = L.v;
}

// direct HBM->LDS DMA, 16B per lane; LDS dest = wave-uniform base + lane*16
__device__ inline void gload_lds16(const void* g, void* l) {
    __builtin_amdgcn_global_load_lds(
        (const __attribute__((address_space(1))) void*)g,
        (__attribute__((address_space(3))) void*)l, 16, 0, 0);
}

// ---------------------------------------------------------------------------
// Kernel 1: pack W_in [64][1024] fp32 -> Wp bf16 hi/lo in MFMA-fragment layout
// Wp layout: [chunk 32][hl 2][kg 4][n 64][j 8]  (ushort), 256 KB total
// ---------------------------------------------------------------------------
__global__ void pack_w_kernel(const float* __restrict__ Win, ushort_t* __restrict__ Wp) {
    int idx = blockIdx.x * 256 + threadIdx.x;   // 0..65535
    int j  = idx & 7;
    int n  = (idx >> 3) & 63;
    int kg = (idx >> 9) & 3;
    int ch = idx >> 11;                          // 0..31
    int k  = ch * 32 + kg * 8 + j;
    float v = Win[n * 1024 + k];
    unsigned hb = f2bf_rnd(v) >> 16;
    float hf = __uint_as_float(hb << 16);
    unsigned lb = f2bf_rnd(v - hf) >> 16;
    Wp[((ch * 2 + 0) * 4 + kg) * 512 + n * 8 + j] = (ushort_t)hb;
    Wp[((ch * 2 + 1) * 4 + kg) * 512 + n * 8 + j] = (ushort_t)lb;
}

// ---------------------------------------------------------------------------
// Kernel 2 (v4b): ext = x @ W_in^T + b_in, bf16 MFMA 3-term split.
// BM=64, BK=64, 256 thr (4 waves x 16 rows).  global_load_lds pipeline,
// RACE-FIXED (R11 bug): issuing tile kt+2 into buf must happen AFTER a
// barrier that closes all waves' compute reads of buf.  Per iteration:
//   s_waitcnt vmcnt(8)   <- tile kt's DMA done; kt+1's stays in flight
//   s_barrier            <- tile kt visible to all waves
//   compute(buf)         <- all ds_reads consumed (lgkm-waited) in here
//   s_barrier            <- all waves done READING buf
//   issue_tile(kt+2,buf) <- DMA into buf now safe; lands during next compute
// ---------------------------------------------------------------------------
__global__ __launch_bounds__(256) void gemm_ext_kernel(const float* __restrict__ x,
                                                       const ushort_t* __restrict__ Wp,
                                                       const float* __restrict__ bin,
                                                       float* __restrict__ ext) {
    __shared__ __align__(16) float    Asm[2][4096];   // 2 x 16 KB, [row][col64]
    __shared__ __align__(16) ushort_t Bsm[2][8192];   // 2 x 16 KB, linear

    const int tid  = threadIdx.x;        // 0..255
    const int lane = tid & 63;
    const int wave = tid >> 6;
    const int l15  = lane & 15;
    const int lg   = lane >> 4;

    const long rowbase = (long)blockIdx.x * 64;

    auto issue_tile = [&](int kt, int buf) {
        const float* xb = x + rowbase * 1024 + kt * 64;
        const ushort_t* wb = Wp + kt * 8192;
#pragma unroll
        for (int i = 0; i < 4; ++i) {
            const int slot = i * 256 + tid;           // = i*256 + wave*64 + lane
            gload_lds16(xb + (long)(slot >> 4) * 1024 + (slot & 15) * 4,
                        &Asm[buf][(i * 256 + wave * 64) * 4]);
        }
#pragma unroll
        for (int i = 0; i < 4; ++i) {
            const int slot = i * 256 + tid;
            gload_lds16(wb + slot * 8,
                        &Bsm[buf][(i * 256 + wave * 64) * 8]);
        }
    };

    f32x4 acc[4];
#pragma unroll
    for (int n = 0; n < 4; ++n) acc[n] = (f32x4){0.f, 0.f, 0.f, 0.f};

    issue_tile(0, 0);
    issue_tile(1, 1);

#pragma unroll 1
    for (int kt = 0; kt < 16; ++kt) {
        const int buf = kt & 1;
        if (kt < 15) {
            asm volatile("s_waitcnt vmcnt(8)" ::: "memory");
        } else {
            asm volatile("s_waitcnt vmcnt(0)" ::: "memory");
        }
        asm volatile("s_barrier" ::: "memory");

#pragma unroll
        for (int kc = 0; kc < 2; ++kc) {
            const float* ap = &Asm[buf][(wave * 16 + l15) * 64 + kc * 32 + lg * 8];
            f32x4 a0 = *(const f32x4*)ap;
            f32x4 a1 = *(const f32x4*)(ap + 4);
            bf16x8 Ahi, Alo;
            split8(a0, a1, Ahi, Alo);
            const ushort_t* bp = &Bsm[buf][kc * 4096 + lg * 512 + l15 * 8];
#pragma unroll
            for (int nq = 0; nq < 4; ++nq) {
                bf16x8 bh = *(const bf16x8*)(bp + nq * 128);
                bf16x8 bl = *(const bf16x8*)(bp + 2048 + nq * 128);
                acc[nq] = __builtin_amdgcn_mfma_f32_16x16x32_bf16(Ahi, bh, acc[nq], 0, 0, 0);
                acc[nq] = __builtin_amdgcn_mfma_f32_16x16x32_bf16(Ahi, bl, acc[nq], 0, 0, 0);
                acc[nq] = __builtin_amdgcn_mfma_f32_16x16x32_bf16(Alo, bh, acc[nq], 0, 0, 0);
            }
        }

        if (kt + 2 < 16) {
            asm volatile("s_barrier" ::: "memory");   // all waves done reading buf
            issue_tile(kt + 2, buf);
        }
    }

    // epilogue: add bias, store.  C/D map: col = lane&15, row = (lane>>4)*4 + r
#pragma unroll
    for (int nq = 0; nq < 4; ++nq) {
        float bias = bin[nq * 16 + l15];
        long r0 = rowbase + wave * 16 + lg * 4;
#pragma unroll
        for (int r = 0; r < 4; ++r) {
            ext[(r0 + r) * 64 + nq * 16 + l15] = acc[nq][r] + bias;
        }
    }
}

// ---------------------------------------------------------------------------
// Kernel 3: ATTRIBUTION PROBE — scan v2 (readlane broadcast) repeated 5x
// inside one dispatch (idempotent).  If per-rep S >~ 63us the dispatch
// crosses the ~315us harness fills and shows in top-5 with counters.
// ---------------------------------------------------------------------------
__device__ inline float rl(float v, int k) {
    return __int_as_float(__builtin_amdgcn_readlane(__float_as_int(v), k));
}

__global__ __launch_bounds__(64) void scan_kernel(const float* __restrict__ ext,
                                                  const float* __restrict__ Wrec,
                                                  const float* __restrict__ brec,
                                                  float* __restrict__ states) {
    const int b = blockIdx.x;
    const int h = threadIdx.x;   // 0..63

    float w[64];
#pragma unroll
    for (int i = 0; i < 16; ++i)
        *(f32x4*)&w[i * 4] = *(const f32x4*)&Wrec[h * 64 + i * 4];
    const float bias = brec[h];

    const float* ep = ext + (size_t)b * 512 * 64 + h;
    float* sp = states + (size_t)b * 512 * 64 + h;

#pragma unroll 1
    for (int rep = 0; rep < 5; ++rep) {
        float s = 0.f;
        float e0 = ep[0];
        float e1 = ep[64];
        float e2 = ep[128];
        float e3 = ep[192];

#define SCAN_STEP(EREG, IDX)                                                   \
    {                                                                          \
        float in = s + EREG;                                                   \
        int tn = t + 4 + (IDX); tn = tn > 511 ? 511 : tn;                      \
        EREG = ep[(size_t)tn * 64];                                            \
        float a0 = bias, a1 = 0.f, a2 = 0.f, a3 = 0.f;                         \
        _Pragma("unroll")                                                      \
        for (int k = 0; k < 64; k += 4) {                                      \
            a0 = fmaf(w[k + 0], rl(in, k + 0), a0);                            \
            a1 = fmaf(w[k + 1], rl(in, k + 1), a1);                            \
            a2 = fmaf(w[k + 2], rl(in, k + 2), a2);                            \
            a3 = fmaf(w[k + 3], rl(in, k + 3), a3);                            \
        }                                                                      \
        s = fmaxf((a0 + a1) + (a2 + a3), 0.f);                                 \
        sp[(size_t)(t + (IDX)) * 64] = s;                                      \
    }

#pragma unroll 1
        for (int t = 0; t < 512; t += 4) {
            SCAN_STEP(e0, 0)
            SCAN_STEP(e1, 1)
            SCAN_STEP(e2, 2)
            SCAN_STEP(e3, 3)
        }
#undef SCAN_STEP
    }
}

// ---------------------------------------------------------------------------
// Kernel 4: output head.  (byte-identical to R4..R11)
// ---------------------------------------------------------------------------
__global__ __launch_bounds__(256) void head_kernel(const float* __restrict__ states,
                                                   const float* __restrict__ Wo1,
                                                   const float* __restrict__ bo1,
                                                   const float* __restrict__ Wo2,
                                                   const float* __restrict__ bo2,
                                                   float* __restrict__ out) {
    __shared__ float W1t[64][32];   // W1t[k][j] = Wo1[j][k]
    __shared__ float w2s[64];
    __shared__ float b1s[32];
    __shared__ float b2s[2];

    const int tid = threadIdx.x;
    for (int idx = tid; idx < 2048; idx += 256) {
        int j = idx >> 6, k = idx & 63;
        W1t[k][j] = Wo1[idx];
    }
    if (tid < 64) w2s[tid] = Wo2[tid];
    if (tid < 32) b1s[tid] = bo1[tid];
    if (tid < 2)  b2s[tid] = bo2[tid];
    __syncthreads();

    const size_t row = (size_t)blockIdx.x * 256 + tid;  // 0..131071
    const float* srow = states + row * 64;

    float st[64];
#pragma unroll
    for (int i = 0; i < 16; ++i)
        *(float4*)&st[i * 4] = *(const float4*)&srow[i * 4];

    float4 hacc[8];
#pragma unroll
    for (int j4 = 0; j4 < 8; ++j4) hacc[j4] = (float4){0.f, 0.f, 0.f, 0.f};

#pragma unroll
    for (int k = 0; k < 64; ++k) {
        float sk = st[k];
#pragma unroll
        for (int j4 = 0; j4 < 8; ++j4) {
            float4 wv = *(const float4*)&W1t[k][j4 * 4];
            hacc[j4].x += sk * wv.x;
            hacc[j4].y += sk * wv.y;
            hacc[j4].z += sk * wv.z;
            hacc[j4].w += sk * wv.w;
        }
    }

    float o0 = b2s[0], o1 = b2s[1];
#pragma unroll
    for (int j4 = 0; j4 < 8; ++j4) {
        float4 bv = *(const float4*)&b1s[j4 * 4];
        float hj[4] = {fmaxf(hacc[j4].x + bv.x, 0.f), fmaxf(hacc[j4].y + bv.y, 0.f),
                       fmaxf(hacc[j4].z + bv.z, 0.f), fmaxf(hacc[j4].w + bv.w, 0.f)};
#pragma unroll
        for (int r = 0; r < 4; ++r) {
            int j = j4 * 4 + r;
            o0 += hj[r] * w2s[j];
            o1 += hj[r] * w2s[32 + j];
        }
    }
    float2 ov = {o0, o1};
    *(float2*)&out[row * 2] = ov;
}

// ---------------------------------------------------------------------------
extern "C" void kernel_launch(void* const* d_in, const int* in_sizes, int n_in,
                              void* d_out, int out_size, void* d_ws, size_t ws_size,
                              hipStream_t stream) {
    (void)in_sizes; (void)n_in; (void)out_size; (void)ws_size;

    const float* x     = (const float*)d_in[0];
    const float* W_in  = (const float*)d_in[1];
    const float* b_in  = (const float*)d_in[2];
    const float* W_rec = (const float*)d_in[3];
    const float* b_rec = (const float*)d_in[4];
    const float* W_o1  = (const float*)d_in[5];
    const float* b_o1  = (const float*)d_in[6];
    const float* W_o2  = (const float*)d_in[7];
    const float* b_o2  = (const float*)d_in[8];
    float* out = (float*)d_out;

    char* ws = (char*)d_ws;
    ushort_t* Wp   = (ushort_t*)ws;                                  // 256 KB
    float* ext     = (float*)(ws + (1u << 20));                      // 32 MB
    float* states  = (float*)(ws + (1u << 20) + (32u << 20));        // 32 MB

    pack_w_kernel<<<256, 256, 0, stream>>>(W_in, Wp);
    gemm_ext_kernel<<<2048, 256, 0, stream>>>(x, Wp, b_in, ext);
    scan_kernel<<<256, 64, 0, stream>>>(ext, W_rec, b_rec, states);   // 5x reps (probe)
    head_kernel<<<512, 256, 0, stream>>>(states, W_o1, b_o1, W_o2, b_o2, out);
}

// Round 13
// 317.140 us; speedup vs baseline: 2.6432x; 2.6432x over previous
//
#include <hip/hip_runtime.h>

typedef __attribute__((ext_vector_type(8))) short bf16x8;
typedef __attribute__((ext_vector_type(4))) float f32x4;
typedef unsigned short ushort_t;

// ---------------------------------------------------------------------------
// fp32 -> bf16 RNE helpers
// ---------------------------------------------------------------------------
__device__ inline unsigned f2bf_rnd(float f) {
    unsigned u = __float_as_uint(f);
    return u + 0x7FFFu + ((u >> 16) & 1u);   // high 16 bits = RNE bf16
}

__device__ inline void split8(f32x4 a, f32x4 b, bf16x8& hv, bf16x8& lv) {
    float f[8] = {a.x, a.y, a.z, a.w, b.x, b.y, b.z, b.w};
    unsigned r[8], l[8];
#pragma unroll
    for (int j = 0; j < 8; ++j) r[j] = f2bf_rnd(f[j]);
#pragma unroll
    for (int j = 0; j < 8; ++j) {
        float hf = __uint_as_float(r[j] & 0xFFFF0000u);
        l[j] = f2bf_rnd(f[j] - hf);
    }
    union { unsigned u[4]; bf16x8 v; } H, L;
#pragma unroll
    for (int p = 0; p < 4; ++p) {
        H.u[p] = __builtin_amdgcn_perm(r[2 * p + 1], r[2 * p], 0x07060302u);
        L.u[p] = __builtin_amdgcn_perm(l[2 * p + 1], l[2 * p], 0x07060302u);
    }
    hv = H.v; lv = L.v;
}

// direct HBM->LDS DMA, 16B per lane; LDS dest = wave-uniform base + lane*16
__device__ inline void gload_lds16(const void* g, void* l) {
    __builtin_amdgcn_global_load_lds(
        (const __attribute__((address_space(1))) void*)g,
        (__attribute__((address_space(3))) void*)l, 16, 0, 0);
}

// ---------------------------------------------------------------------------
// Kernel 1: pack W_in [64][1024] fp32 -> Wp bf16 hi/lo in MFMA-fragment layout
// Wp layout: [chunk 32][hl 2][kg 4][n 64][j 8]  (ushort), 256 KB total
// ---------------------------------------------------------------------------
__global__ void pack_w_kernel(const float* __restrict__ Win, ushort_t* __restrict__ Wp) {
    int idx = blockIdx.x * 256 + threadIdx.x;   // 0..65535
    int j  = idx & 7;
    int n  = (idx >> 3) & 63;
    int kg = (idx >> 9) & 3;
    int ch = idx >> 11;                          // 0..31
    int k  = ch * 32 + kg * 8 + j;
    float v = Win[n * 1024 + k];
    unsigned hb = f2bf_rnd(v) >> 16;
    float hf = __uint_as_float(hb << 16);
    unsigned lb = f2bf_rnd(v - hf) >> 16;
    Wp[((ch * 2 + 0) * 4 + kg) * 512 + n * 8 + j] = (ushort_t)hb;
    Wp[((ch * 2 + 1) * 4 + kg) * 512 + n * 8 + j] = (ushort_t)lb;
}

// ---------------------------------------------------------------------------
// Kernel 2 (v5): ext = x @ W_in^T + b_in, bf16 MFMA 3-term split.
// BM=64, BK=64, 256 thr (4 waves x 16 rows).  global_load_lds pipeline with
// EARLY READS: per tile, all LDS->reg reads happen first, then lgkmcnt(0) +
// barrier, then tile kt+2's DMA is issued BEFORE compute (split8+MFMA), so
// the prefetch overlaps the whole VALU/MFMA phase.
//   vmcnt(8); s_barrier          <- tile kt DMA'd & visible; kt+1 in flight
//   ds_read A(4xb128) B(16xb128) -> regs
//   lgkmcnt(0); s_barrier        <- all waves done reading buf
//   issue_tile(kt+2, buf)        <- DMA safe, lands during compute
//   split8 + MFMA from regs
// ---------------------------------------------------------------------------
__global__ __launch_bounds__(256) void gemm_ext_kernel(const float* __restrict__ x,
                                                       const ushort_t* __restrict__ Wp,
                                                       const float* __restrict__ bin,
                                                       float* __restrict__ ext) {
    __shared__ __align__(16) float    Asm[2][4096];   // 2 x 16 KB, [row][col64]
    __shared__ __align__(16) ushort_t Bsm[2][8192];   // 2 x 16 KB, linear

    const int tid  = threadIdx.x;        // 0..255
    const int lane = tid & 63;
    const int wave = tid >> 6;
    const int l15  = lane & 15;
    const int lg   = lane >> 4;

    const long rowbase = (long)blockIdx.x * 64;

    auto issue_tile = [&](int kt, int buf) {
        const float* xb = x + rowbase * 1024 + kt * 64;
        const ushort_t* wb = Wp + kt * 8192;
#pragma unroll
        for (int i = 0; i < 4; ++i) {
            const int slot = i * 256 + tid;           // = i*256 + wave*64 + lane
            gload_lds16(xb + (long)(slot >> 4) * 1024 + (slot & 15) * 4,
                        &Asm[buf][(i * 256 + wave * 64) * 4]);
        }
#pragma unroll
        for (int i = 0; i < 4; ++i) {
            const int slot = i * 256 + tid;
            gload_lds16(wb + slot * 8,
                        &Bsm[buf][(i * 256 + wave * 64) * 8]);
        }
    };

    f32x4 acc[4];
#pragma unroll
    for (int n = 0; n < 4; ++n) acc[n] = (f32x4){0.f, 0.f, 0.f, 0.f};

    issue_tile(0, 0);
    issue_tile(1, 1);

#pragma unroll 1
    for (int kt = 0; kt < 16; ++kt) {
        const int buf = kt & 1;
        if (kt < 15) {
            asm volatile("s_waitcnt vmcnt(8)" ::: "memory");
        } else {
            asm volatile("s_waitcnt vmcnt(0)" ::: "memory");
        }
        asm volatile("s_barrier" ::: "memory");

        // ---- all LDS reads for this tile, up front ----
        f32x4 a[2][2];
        bf16x8 bh[2][4], bl[2][4];
#pragma unroll
        for (int kc = 0; kc < 2; ++kc) {
            const float* ap = &Asm[buf][(wave * 16 + l15) * 64 + kc * 32 + lg * 8];
            a[kc][0] = *(const f32x4*)ap;
            a[kc][1] = *(const f32x4*)(ap + 4);
            const ushort_t* bp = &Bsm[buf][kc * 4096 + lg * 512 + l15 * 8];
#pragma unroll
            for (int nq = 0; nq < 4; ++nq) {
                bh[kc][nq] = *(const bf16x8*)(bp + nq * 128);
                bl[kc][nq] = *(const bf16x8*)(bp + 2048 + nq * 128);
            }
        }
        asm volatile("s_waitcnt lgkmcnt(0)" ::: "memory");
        asm volatile("s_barrier" ::: "memory");       // all waves done reading buf

        if (kt + 2 < 16) issue_tile(kt + 2, buf);     // overlaps compute below

        // ---- compute from registers ----
#pragma unroll
        for (int kc = 0; kc < 2; ++kc) {
            bf16x8 Ahi, Alo;
            split8(a[kc][0], a[kc][1], Ahi, Alo);
#pragma unroll
            for (int nq = 0; nq < 4; ++nq) {
                acc[nq] = __builtin_amdgcn_mfma_f32_16x16x32_bf16(Ahi, bh[kc][nq], acc[nq], 0, 0, 0);
                acc[nq] = __builtin_amdgcn_mfma_f32_16x16x32_bf16(Ahi, bl[kc][nq], acc[nq], 0, 0, 0);
                acc[nq] = __builtin_amdgcn_mfma_f32_16x16x32_bf16(Alo, bh[kc][nq], acc[nq], 0, 0, 0);
            }
        }
    }

    // epilogue: add bias, store.  C/D map: col = lane&15, row = (lane>>4)*4 + r
#pragma unroll
    for (int nq = 0; nq < 4; ++nq) {
        float bias = bin[nq * 16 + l15];
        long r0 = rowbase + wave * 16 + lg * 4;
#pragma unroll
        for (int r = 0; r < 4; ++r) {
            ext[(r0 + r) * 64 + nq * 16 + l15] = acc[nq][r] + bias;
        }
    }
}

// ---------------------------------------------------------------------------
// Kernel 3 (v3): recurrent scan, readlane broadcast with SOFTWARE-PIPELINED
// readlane groups: group g+1's 8 readlanes are issued before group g's fmas,
// hiding readlane->fma dependency latency (R12 probe: 650 cyc/step, ~400 of
// which were these stalls).  Single rep (probe removed).
// ---------------------------------------------------------------------------
__device__ inline float rl(float v, int k) {
    return __int_as_float(__builtin_amdgcn_readlane(__float_as_int(v), k));
}

__global__ __launch_bounds__(64) void scan_kernel(const float* __restrict__ ext,
                                                  const float* __restrict__ Wrec,
                                                  const float* __restrict__ brec,
                                                  float* __restrict__ states) {
    const int b = blockIdx.x;
    const int h = threadIdx.x;   // 0..63

    float w[64];
#pragma unroll
    for (int i = 0; i < 16; ++i)
        *(f32x4*)&w[i * 4] = *(const f32x4*)&Wrec[h * 64 + i * 4];
    const float bias = brec[h];

    const float* ep = ext + (size_t)b * 512 * 64 + h;
    float* sp = states + (size_t)b * 512 * 64 + h;

    float s = 0.f;
    float e0 = ep[0];
    float e1 = ep[64];
    float e2 = ep[128];
    float e3 = ep[192];

#define SCAN_STEP(EREG, IDX)                                                    \
    {                                                                           \
        float in = s + EREG;                                                    \
        int tn = t + 4 + (IDX); tn = tn > 511 ? 511 : tn;                       \
        EREG = ep[(size_t)tn * 64];                                             \
        float rr[2][8];                                                         \
        _Pragma("unroll")                                                       \
        for (int j = 0; j < 8; ++j) rr[0][j] = rl(in, j);                       \
        float a[4] = {bias, 0.f, 0.f, 0.f};                                     \
        _Pragma("unroll")                                                       \
        for (int g = 0; g < 8; ++g) {                                           \
            const int cur = g & 1;                                              \
            if (g < 7) {                                                        \
                _Pragma("unroll")                                               \
                for (int j = 0; j < 8; ++j)                                     \
                    rr[cur ^ 1][j] = rl(in, (g + 1) * 8 + j);                   \
            }                                                                   \
            _Pragma("unroll")                                                   \
            for (int j = 0; j < 8; ++j)                                         \
                a[j & 3] = fmaf(w[g * 8 + j], rr[cur][j], a[j & 3]);            \
        }                                                                       \
        s = fmaxf((a[0] + a[1]) + (a[2] + a[3]), 0.f);                          \
        sp[(size_t)(t + (IDX)) * 64] = s;                                       \
    }

#pragma unroll 1
    for (int t = 0; t < 512; t += 4) {
        SCAN_STEP(e0, 0)
        SCAN_STEP(e1, 1)
        SCAN_STEP(e2, 2)
        SCAN_STEP(e3, 3)
    }
#undef SCAN_STEP
}

// ---------------------------------------------------------------------------
// Kernel 4: output head.  (byte-identical to R4..R12)
// ---------------------------------------------------------------------------
__global__ __launch_bounds__(256) void head_kernel(const float* __restrict__ states,
                                                   const float* __restrict__ Wo1,
                                                   const float* __restrict__ bo1,
                                                   const float* __restrict__ Wo2,
                                                   const float* __restrict__ bo2,
                                                   float* __restrict__ out) {
    __shared__ float W1t[64][32];   // W1t[k][j] = Wo1[j][k]
    __shared__ float w2s[64];
    __shared__ float b1s[32];
    __shared__ float b2s[2];

    const int tid = threadIdx.x;
    for (int idx = tid; idx < 2048; idx += 256) {
        int j = idx >> 6, k = idx & 63;
        W1t[k][j] = Wo1[idx];
    }
    if (tid < 64) w2s[tid] = Wo2[tid];
    if (tid < 32) b1s[tid] = bo1[tid];
    if (tid < 2)  b2s[tid] = bo2[tid];
    __syncthreads();

    const size_t row = (size_t)blockIdx.x * 256 + tid;  // 0..131071
    const float* srow = states + row * 64;

    float st[64];
#pragma unroll
    for (int i = 0; i < 16; ++i)
        *(float4*)&st[i * 4] = *(const float4*)&srow[i * 4];

    float4 hacc[8];
#pragma unroll
    for (int j4 = 0; j4 < 8; ++j4) hacc[j4] = (float4){0.f, 0.f, 0.f, 0.f};

#pragma unroll
    for (int k = 0; k < 64; ++k) {
        float sk = st[k];
#pragma unroll
        for (int j4 = 0; j4 < 8; ++j4) {
            float4 wv = *(const float4*)&W1t[k][j4 * 4];
            hacc[j4].x += sk * wv.x;
            hacc[j4].y += sk * wv.y;
            hacc[j4].z += sk * wv.z;
            hacc[j4].w += sk * wv.w;
        }
    }

    float o0 = b2s[0], o1 = b2s[1];
#pragma unroll
    for (int j4 = 0; j4 < 8; ++j4) {
        float4 bv = *(const float4*)&b1s[j4 * 4];
        float hj[4] = {fmaxf(hacc[j4].x + bv.x, 0.f), fmaxf(hacc[j4].y + bv.y, 0.f),
                       fmaxf(hacc[j4].z + bv.z, 0.f), fmaxf(hacc[j4].w + bv.w, 0.f)};
#pragma unroll
        for (int r = 0; r < 4; ++r) {
            int j = j4 * 4 + r;
            o0 += hj[r] * w2s[j];
            o1 += hj[r] * w2s[32 + j];
        }
    }
    float2 ov = {o0, o1};
    *(float2*)&out[row * 2] = ov;
}

// ---------------------------------------------------------------------------
extern "C" void kernel_launch(void* const* d_in, const int* in_sizes, int n_in,
                              void* d_out, int out_size, void* d_ws, size_t ws_size,
                              hipStream_t stream) {
    (void)in_sizes; (void)n_in; (void)out_size; (void)ws_size;

    const float* x     = (const float*)d_in[0];
    const float* W_in  = (const float*)d_in[1];
    const float* b_in  = (const float*)d_in[2];
    const float* W_rec = (const float*)d_in[3];
    const float* b_rec = (const float*)d_in[4];
    const float* W_o1  = (const float*)d_in[5];
    const float* b_o1  = (const float*)d_in[6];
    const float* W_o2  = (const float*)d_in[7];
    const float* b_o2  = (const float*)d_in[8];
    float* out = (float*)d_out;

    char* ws = (char*)d_ws;
    ushort_t* Wp   = (ushort_t*)ws;                                  // 256 KB
    float* ext     = (float*)(ws + (1u << 20));                      // 32 MB
    float* states  = (float*)(ws + (1u << 20) + (32u << 20));        // 32 MB

    pack_w_kernel<<<256, 256, 0, stream>>>(W_in, Wp);
    gemm_ext_kernel<<<2048, 256, 0, stream>>>(x, Wp, b_in, ext);
    scan_kernel<<<256, 64, 0, stream>>>(ext, W_rec, b_rec, states);
    head_kernel<<<512, 256, 0, stream>>>(states, W_o1, b_o1, W_o2, b_o2, out);
}

// Round 14
// 273.782 us; speedup vs baseline: 3.0618x; 1.1584x over previous
//
#include <hip/hip_runtime.h>

typedef __attribute__((ext_vector_type(8))) short bf16x8;
typedef __attribute__((ext_vector_type(4))) float f32x4;
typedef unsigned short ushort_t;

// ---------------------------------------------------------------------------
// fp32 -> bf16 RNE helpers
// ---------------------------------------------------------------------------
__device__ inline unsigned f2bf_rnd(float f) {
    unsigned u = __float_as_uint(f);
    return u + 0x7FFFu + ((u >> 16) & 1u);   // high 16 bits = RNE bf16
}

__device__ inline void split8(f32x4 a, f32x4 b, bf16x8& hv, bf16x8& lv) {
    float f[8] = {a.x, a.y, a.z, a.w, b.x, b.y, b.z, b.w};
    unsigned r[8], l[8];
#pragma unroll
    for (int j = 0; j < 8; ++j) r[j] = f2bf_rnd(f[j]);
#pragma unroll
    for (int j = 0; j < 8; ++j) {
        float hf = __uint_as_float(r[j] & 0xFFFF0000u);
        l[j] = f2bf_rnd(f[j] - hf);
    }
    union { unsigned u[4]; bf16x8 v; } H, L;
#pragma unroll
    for (int p = 0; p < 4; ++p) {
        H.u[p] = __builtin_amdgcn_perm(r[2 * p + 1], r[2 * p], 0x07060302u);
        L.u[p] = __builtin_amdgcn_perm(l[2 * p + 1], l[2 * p], 0x07060302u);
    }
    hv = H.v; lv = L.v;
}

// direct HBM->LDS DMA, 16B per lane; LDS dest = wave-uniform base + lane*16
__device__ inline void gload_lds16(const void* g, void* l) {
    __builtin_amdgcn_global_load_lds(
        (const __attribute__((address_space(1))) void*)g,
        (__attribute__((address_space(3))) void*)l, 16, 0, 0);
}

// ---------------------------------------------------------------------------
// Kernel 1: pack W_in [64][1024] fp32 -> Wp bf16 hi/lo in MFMA-fragment layout
// Wp layout: [chunk 32][hl 2][kg 4][n 64][j 8]  (ushort), 256 KB total
// ---------------------------------------------------------------------------
__global__ void pack_w_kernel(const float* __restrict__ Win, ushort_t* __restrict__ Wp) {
    int idx = blockIdx.x * 256 + threadIdx.x;   // 0..65535
    int j  = idx & 7;
    int n  = (idx >> 3) & 63;
    int kg = (idx >> 9) & 3;
    int ch = idx >> 11;                          // 0..31
    int k  = ch * 32 + kg * 8 + j;
    float v = Win[n * 1024 + k];
    unsigned hb = f2bf_rnd(v) >> 16;
    float hf = __uint_as_float(hb << 16);
    unsigned lb = f2bf_rnd(v - hf) >> 16;
    Wp[((ch * 2 + 0) * 4 + kg) * 512 + n * 8 + j] = (ushort_t)hb;
    Wp[((ch * 2 + 1) * 4 + kg) * 512 + n * 8 + j] = (ushort_t)lb;
}

// ---------------------------------------------------------------------------
// Kernel 2 (v4b, byte-revert to R12's measured 131us): global_load_lds
// pipeline, counted vmcnt, two barriers/tile, compiler-interleaved ds_reads.
//   vmcnt(8); s_barrier  <- tile kt DMA'd & visible; kt+1 in flight
//   compute(buf)         <- ds_reads interleaved with MFMA by compiler
//   s_barrier            <- all waves done reading buf
//   issue_tile(kt+2,buf)
// ---------------------------------------------------------------------------
__global__ __launch_bounds__(256) void gemm_ext_kernel(const float* __restrict__ x,
                                                       const ushort_t* __restrict__ Wp,
                                                       const float* __restrict__ bin,
                                                       float* __restrict__ ext) {
    __shared__ __align__(16) float    Asm[2][4096];   // 2 x 16 KB, [row][col64]
    __shared__ __align__(16) ushort_t Bsm[2][8192];   // 2 x 16 KB, linear

    const int tid  = threadIdx.x;        // 0..255
    const int lane = tid & 63;
    const int wave = tid >> 6;
    const int l15  = lane & 15;
    const int lg   = lane >> 4;

    const long rowbase = (long)blockIdx.x * 64;

    auto issue_tile = [&](int kt, int buf) {
        const float* xb = x + rowbase * 1024 + kt * 64;
        const ushort_t* wb = Wp + kt * 8192;
#pragma unroll
        for (int i = 0; i < 4; ++i) {
            const int slot = i * 256 + tid;           // = i*256 + wave*64 + lane
            gload_lds16(xb + (long)(slot >> 4) * 1024 + (slot & 15) * 4,
                        &Asm[buf][(i * 256 + wave * 64) * 4]);
        }
#pragma unroll
        for (int i = 0; i < 4; ++i) {
            const int slot = i * 256 + tid;
            gload_lds16(wb + slot * 8,
                        &Bsm[buf][(i * 256 + wave * 64) * 8]);
        }
    };

    f32x4 acc[4];
#pragma unroll
    for (int n = 0; n < 4; ++n) acc[n] = (f32x4){0.f, 0.f, 0.f, 0.f};

    issue_tile(0, 0);
    issue_tile(1, 1);

#pragma unroll 1
    for (int kt = 0; kt < 16; ++kt) {
        const int buf = kt & 1;
        if (kt < 15) {
            asm volatile("s_waitcnt vmcnt(8)" ::: "memory");
        } else {
            asm volatile("s_waitcnt vmcnt(0)" ::: "memory");
        }
        asm volatile("s_barrier" ::: "memory");

#pragma unroll
        for (int kc = 0; kc < 2; ++kc) {
            const float* ap = &Asm[buf][(wave * 16 + l15) * 64 + kc * 32 + lg * 8];
            f32x4 a0 = *(const f32x4*)ap;
            f32x4 a1 = *(const f32x4*)(ap + 4);
            bf16x8 Ahi, Alo;
            split8(a0, a1, Ahi, Alo);
            const ushort_t* bp = &Bsm[buf][kc * 4096 + lg * 512 + l15 * 8];
#pragma unroll
            for (int nq = 0; nq < 4; ++nq) {
                bf16x8 bh = *(const bf16x8*)(bp + nq * 128);
                bf16x8 bl = *(const bf16x8*)(bp + 2048 + nq * 128);
                acc[nq] = __builtin_amdgcn_mfma_f32_16x16x32_bf16(Ahi, bh, acc[nq], 0, 0, 0);
                acc[nq] = __builtin_amdgcn_mfma_f32_16x16x32_bf16(Ahi, bl, acc[nq], 0, 0, 0);
                acc[nq] = __builtin_amdgcn_mfma_f32_16x16x32_bf16(Alo, bh, acc[nq], 0, 0, 0);
            }
        }

        if (kt + 2 < 16) {
            asm volatile("s_barrier" ::: "memory");   // all waves done reading buf
            issue_tile(kt + 2, buf);
        }
    }

    // epilogue: add bias, store.  C/D map: col = lane&15, row = (lane>>4)*4 + r
#pragma unroll
    for (int nq = 0; nq < 4; ++nq) {
        float bias = bin[nq * 16 + l15];
        long r0 = rowbase + wave * 16 + lg * 4;
#pragma unroll
        for (int r = 0; r < 4; ++r) {
            ext[(r0 + r) * 64 + nq * 16 + l15] = acc[nq][r] + bias;
        }
    }
}

// ---------------------------------------------------------------------------
// Kernel 3 (v4): readlane scan with sched_barrier(0)-PINNED groups.
// R12 probe: 650 cyc/step, ~400 of it rl->fma SGPR-hazard stalls (compiler
// pairs each readlane with its consuming fma).  v3's source-level grouping
// was re-scheduled away (R13 neutral).  v4 pins: 16 readlanes issued one
// full group ahead of their fmas, sched_barrier(0) after every group so
// nothing can be re-paired.  Issue floor ~256 cyc/step.
// ---------------------------------------------------------------------------
__device__ inline float rl(float v, int k) {
    return __int_as_float(__builtin_amdgcn_readlane(__float_as_int(v), k));
}

__global__ __launch_bounds__(64) void scan_kernel(const float* __restrict__ ext,
                                                  const float* __restrict__ Wrec,
                                                  const float* __restrict__ brec,
                                                  float* __restrict__ states) {
    const int b = blockIdx.x;
    const int h = threadIdx.x;   // 0..63

    float w[64];
#pragma unroll
    for (int i = 0; i < 16; ++i)
        *(f32x4*)&w[i * 4] = *(const f32x4*)&Wrec[h * 64 + i * 4];
    const float bias = brec[h];

    const float* ep = ext + (size_t)b * 512 * 64 + h;
    float* sp = states + (size_t)b * 512 * 64 + h;

    float s = 0.f;
    float e0 = ep[0];
    float e1 = ep[64];
    float e2 = ep[128];
    float e3 = ep[192];

#define RLG(DST, BASE)                                                          \
    _Pragma("unroll")                                                           \
    for (int j = 0; j < 16; ++j) DST[j] = rl(in, (BASE) + j);                   \
    __builtin_amdgcn_sched_barrier(0);

#define FMAG(SRC, BASE)                                                         \
    _Pragma("unroll")                                                           \
    for (int j = 0; j < 16; ++j)                                                \
        a[j & 3] = fmaf(w[(BASE) + j], SRC[j], a[j & 3]);                       \
    __builtin_amdgcn_sched_barrier(0);

#define SCAN_STEP(EREG, IDX)                                                    \
    {                                                                           \
        float in = s + EREG;                                                    \
        int tn = t + 4 + (IDX); tn = tn > 511 ? 511 : tn;                       \
        EREG = ep[(size_t)tn * 64];                                             \
        float ra[16], rb[16];                                                   \
        float a[4] = {bias, 0.f, 0.f, 0.f};                                     \
        RLG(ra, 0)                                                              \
        RLG(rb, 16)                                                             \
        FMAG(ra, 0)                                                             \
        RLG(ra, 32)                                                             \
        FMAG(rb, 16)                                                            \
        RLG(rb, 48)                                                             \
        FMAG(ra, 32)                                                            \
        FMAG(rb, 48)                                                            \
        s = fmaxf((a[0] + a[1]) + (a[2] + a[3]), 0.f);                          \
        sp[(size_t)(t + (IDX)) * 64] = s;                                       \
    }

#pragma unroll 1
    for (int t = 0; t < 512; t += 4) {
        SCAN_STEP(e0, 0)
        SCAN_STEP(e1, 1)
        SCAN_STEP(e2, 2)
        SCAN_STEP(e3, 3)
    }
#undef SCAN_STEP
#undef RLG
#undef FMAG
}

// ---------------------------------------------------------------------------
// Kernel 4: output head.  (byte-identical to R4..R13)
// ---------------------------------------------------------------------------
__global__ __launch_bounds__(256) void head_kernel(const float* __restrict__ states,
                                                   const float* __restrict__ Wo1,
                                                   const float* __restrict__ bo1,
                                                   const float* __restrict__ Wo2,
                                                   const float* __restrict__ bo2,
                                                   float* __restrict__ out) {
    __shared__ float W1t[64][32];   // W1t[k][j] = Wo1[j][k]
    __shared__ float w2s[64];
    __shared__ float b1s[32];
    __shared__ float b2s[2];

    const int tid = threadIdx.x;
    for (int idx = tid; idx < 2048; idx += 256) {
        int j = idx >> 6, k = idx & 63;
        W1t[k][j] = Wo1[idx];
    }
    if (tid < 64) w2s[tid] = Wo2[tid];
    if (tid < 32) b1s[tid] = bo1[tid];
    if (tid < 2)  b2s[tid] = bo2[tid];
    __syncthreads();

    const size_t row = (size_t)blockIdx.x * 256 + tid;  // 0..131071
    const float* srow = states + row * 64;

    float st[64];
#pragma unroll
    for (int i = 0; i < 16; ++i)
        *(float4*)&st[i * 4] = *(const float4*)&srow[i * 4];

    float4 hacc[8];
#pragma unroll
    for (int j4 = 0; j4 < 8; ++j4) hacc[j4] = (float4){0.f, 0.f, 0.f, 0.f};

#pragma unroll
    for (int k = 0; k < 64; ++k) {
        float sk = st[k];
#pragma unroll
        for (int j4 = 0; j4 < 8; ++j4) {
            float4 wv = *(const float4*)&W1t[k][j4 * 4];
            hacc[j4].x += sk * wv.x;
            hacc[j4].y += sk * wv.y;
            hacc[j4].z += sk * wv.z;
            hacc[j4].w += sk * wv.w;
        }
    }

    float o0 = b2s[0], o1 = b2s[1];
#pragma unroll
    for (int j4 = 0; j4 < 8; ++j4) {
        float4 bv = *(const float4*)&b1s[j4 * 4];
        float hj[4] = {fmaxf(hacc[j4].x + bv.x, 0.f), fmaxf(hacc[j4].y + bv.y, 0.f),
                       fmaxf(hacc[j4].z + bv.z, 0.f), fmaxf(hacc[j4].w + bv.w, 0.f)};
#pragma unroll
        for (int r = 0; r < 4; ++r) {
            int j = j4 * 4 + r;
            o0 += hj[r] * w2s[j];
            o1 += hj[r] * w2s[32 + j];
        }
    }
    float2 ov = {o0, o1};
    *(float2*)&out[row * 2] = ov;
}

// ---------------------------------------------------------------------------
extern "C" void kernel_launch(void* const* d_in, const int* in_sizes, int n_in,
                              void* d_out, int out_size, void* d_ws, size_t ws_size,
                              hipStream_t stream) {
    (void)in_sizes; (void)n_in; (void)out_size; (void)ws_size;

    const float* x     = (const float*)d_in[0];
    const float* W_in  = (const float*)d_in[1];
    const float* b_in  = (const float*)d_in[2];
    const float* W_rec = (const float*)d_in[3];
    const float* b_rec = (const float*)d_in[4];
    const float* W_o1  = (const float*)d_in[5];
    const float* b_o1  = (const float*)d_in[6];
    const float* W_o2  = (const float*)d_in[7];
    const float* b_o2  = (const float*)d_in[8];
    float* out = (float*)d_out;

    char* ws = (char*)d_ws;
    ushort_t* Wp   = (ushort_t*)ws;                                  // 256 KB
    float* ext     = (float*)(ws + (1u << 20));                      // 32 MB
    float* states  = (float*)(ws + (1u << 20) + (32u << 20));        // 32 MB

    pack_w_kernel<<<256, 256, 0, stream>>>(W_in, Wp);
    gemm_ext_kernel<<<2048, 256, 0, stream>>>(x, Wp, b_in, ext);
    scan_kernel<<<256, 64, 0, stream>>>(ext, W_rec, b_rec, states);
    head_kernel<<<512, 256, 0, stream>>>(states, W_o1, b_o1, W_o2, b_o2, out);
}